// Round 11
// baseline (210.233 us; speedup 1.0000x reference)
//
#include <hip/hip_runtime.h>
#include <hip/hip_bf16.h>
#include <stdint.h>

#define Bb 4
#define Nn 2048
#define Dd 1024
#define Hh 16
#define DHd 64
#define Mm (Bb*Nn)     /* 8192 */
#define D3 (3*Dd)      /* 3072 */

typedef unsigned short u16;
typedef unsigned int u32;
typedef __attribute__((ext_vector_type(8))) short bf16x8;
typedef __attribute__((ext_vector_type(4))) float f32x4;
typedef __attribute__((ext_vector_type(2))) unsigned int u32x2;
typedef __attribute__((ext_vector_type(4))) unsigned int u32x4;

__device__ __forceinline__ u16 f2bf(float f) {
    unsigned int u = __float_as_uint(f);
    u = (u + 0x7FFFu + ((u >> 16) & 1u)) >> 16;
    return (u16)u;
}

__device__ __forceinline__ u32 cvtpk_bf16(float lo, float hi) {
    u32 r;
    asm("v_cvt_pk_bf16_f32 %0, %1, %2" : "=v"(r) : "v"(lo), "v"(hi));
    return r;
}

// bare HW exp2 — no libm guards (inputs bounded by defer-max; -huge underflows to 0)
__device__ __forceinline__ float fexp2(float x) {
    float r;
    asm("v_exp_f32 %0, %1" : "=v"(r) : "v"(x));
    return r;
}

#define GLOAD16(g, l)                                                          \
    __builtin_amdgcn_global_load_lds(                                          \
        (const __attribute__((address_space(1))) unsigned int*)(g),            \
        (__attribute__((address_space(3))) unsigned int*)(l), 16, 0, 0)

// ---------------- fp32 -> bf16 convert ----------------
__global__ void cvt_f32_bf16(const float* __restrict__ in, u16* __restrict__ out, int n4) {
    int i = blockIdx.x * blockDim.x + threadIdx.x;
    int stride = gridDim.x * blockDim.x;
    for (; i < n4; i += stride) {
        float4 v = ((const float4*)in)[i];
        u16 o0 = f2bf(v.x), o1 = f2bf(v.y), o2 = f2bf(v.z), o3 = f2bf(v.w);
        unsigned int lo = (unsigned int)o0 | ((unsigned int)o1 << 16);
        unsigned int hi = (unsigned int)o2 | ((unsigned int)o3 << 16);
        ((uint2*)out)[i] = make_uint2(lo, hi);
    }
}

// convert with scale s applied to flat elements [0, cut4*4) — folds softmax
// scale (and log2e) into the Q-projection rows of W_qkv
__global__ void cvt_f32_bf16_s(const float* __restrict__ in, u16* __restrict__ out,
                               int n4, int cut4, float s) {
    int i = blockIdx.x * blockDim.x + threadIdx.x;
    int stride = gridDim.x * blockDim.x;
    for (; i < n4; i += stride) {
        float4 v = ((const float4*)in)[i];
        float sc = (i < cut4) ? s : 1.0f;
        u16 o0 = f2bf(v.x * sc), o1 = f2bf(v.y * sc), o2 = f2bf(v.z * sc), o3 = f2bf(v.w * sc);
        unsigned int lo = (unsigned int)o0 | ((unsigned int)o1 << 16);
        unsigned int hi = (unsigned int)o2 | ((unsigned int)o3 << 16);
        ((uint2*)out)[i] = make_uint2(lo, hi);
    }
}

// ---------------- bf16 GEMM: C[M][N] = A[M][K] * B[N][K]^T ----------------
// 128x128 tile, BK=64, 256 threads (4 waves 2x2). LDS rows 128B, XOR-swizzled
// at 16B chunks (chunk ^= row&7) via pre-swizzled global source (linear dest).
template<int OUT_F32>
__global__ __launch_bounds__(256) void gemm_bt(const u16* __restrict__ A,
                                               const u16* __restrict__ Bm,
                                               void* __restrict__ C,
                                               int M, int Nout, int K) {
    __shared__ u16 As[128 * 64];
    __shared__ u16 Bs[128 * 64];
    const int t = threadIdx.x;
    const int lane = t & 63;
    const int w = t >> 6;
    const int wr = w >> 1, wc = w & 1;
    const int l15 = lane & 15, l4 = lane >> 4;
    const int m0 = blockIdx.y * 128;
    const int n0 = blockIdx.x * 128;

    f32x4 acc[4][4] = {};

    for (int k0 = 0; k0 < K; k0 += 64) {
        __syncthreads();
#pragma unroll
        for (int i = 0; i < 4; i++) {
            int chunk = i * 256 + t;
            int row = chunk >> 3;
            int csw = ((chunk & 7) ^ (row & 7)) << 3;
            GLOAD16(A + (size_t)(m0 + row) * K + k0 + csw, &As[chunk * 8]);
            GLOAD16(Bm + (size_t)(n0 + row) * K + k0 + csw, &Bs[chunk * 8]);
        }
        __syncthreads();

#pragma unroll
        for (int kh = 0; kh < 2; kh++) {
            bf16x8 a[4], b[4];
#pragma unroll
            for (int mi = 0; mi < 4; mi++) {
                int row = wr * 64 + mi * 16 + l15;
                a[mi] = *(const bf16x8*)&As[row * 64 + (((kh * 4 + l4) ^ (row & 7)) << 3)];
            }
#pragma unroll
            for (int nj = 0; nj < 4; nj++) {
                int row = wc * 64 + nj * 16 + l15;
                b[nj] = *(const bf16x8*)&Bs[row * 64 + (((kh * 4 + l4) ^ (row & 7)) << 3)];
            }
#pragma unroll
            for (int mi = 0; mi < 4; mi++)
#pragma unroll
                for (int nj = 0; nj < 4; nj++)
                    acc[mi][nj] = __builtin_amdgcn_mfma_f32_16x16x32_bf16(a[mi], b[nj], acc[mi][nj], 0, 0, 0);
        }
    }

#pragma unroll
    for (int mi = 0; mi < 4; mi++) {
#pragma unroll
        for (int nj = 0; nj < 4; nj++) {
            int col = n0 + wc * 64 + nj * 16 + l15;
#pragma unroll
            for (int r = 0; r < 4; r++) {
                int row = m0 + wr * 64 + mi * 16 + l4 * 4 + r;
                float v = acc[mi][nj][r];
                if (OUT_F32)
                    ((float*)C)[(size_t)row * Nout + col] = v;
                else
                    ((u16*)C)[(size_t)row * Nout + col] = f2bf(v);
            }
        }
    }
}

// ---------------- causal flash attention ----------------
// grid: (8, 64), 1024 threads = 16 waves. XCD remap: bh = bx*8+(by&7).
// k-PARITY SPLIT: wave w (wl=w&7, par=w>>3) owns q-rows [q0+16wl, +16) and
// processes k-tiles with (kt&1)==par. Waves 0-7 stage K (global_load_lds,
// pre-swizzled src), waves 8-15 reg-stage V transposed. Per pass, the two
// parity-partial online-softmax states merge in-block via an LDS pool that
// OVERLAPS the K/V buffers (safe: merge after last-tile barrier; next pass
// re-stages after another barrier). launch_bounds(1024,2): VGPR cap 64
// (min-blocks semantics, r8), kernel needs ~56.
__global__ __launch_bounds__(1024, 2) void attn(const u16* __restrict__ qkv, u16* __restrict__ y) {
    __shared__ __align__(16) char pool[35328];
    u16 (*Kt)[4096] = reinterpret_cast<u16(*)[4096]>(pool);            // [2][64*64]
    u16 (*Vt)[4096] = reinterpret_cast<u16(*)[4096]>(pool + 16384);    // [2][64*64]
    float* MO = (float*)pool;                  // [8][64][16]  (overlaps K/V)
    float* ML = (float*)(pool + 32768);        // [8][64]
    float* MM = (float*)(pool + 34816);        // [8][16]

    const int t = threadIdx.x;
    const int lane = t & 63;
    const int w = t >> 6;            // 0..15
    const int wl = w & 7;            // q-group
    const int par = w >> 3;          // k parity
    const int l15 = lane & 15, l4 = lane >> 4;
    const int bh = blockIdx.x * 8 + (blockIdx.y & 7);   // XCD-local K/V
    const int pairidx = blockIdx.y >> 3;
    const int b = bh >> 4, h = bh & 15;

    const u16* qbase = qkv + (size_t)(b * Nn) * D3 + h * DHd;
    const u16* Kg = qbase + Dd;
    const u16* Vg = qbase + 2 * Dd;

    // staging maps: waves 0-7 stage K (t in [0,512)), waves 8-15 stage V
    const int krow = t >> 3;                 // valid for t<512
    const int ksw = (((t & 7) ^ (krow & 7)) << 3);
    const int tv = t & 511;                  // for upper half
    const int vi = tv & 31;                  // V: row pair (2vi, 2vi+1)
    const int vsd = (tv >> 5) * 4;           // dims vsd..vsd+3
    const int vchunk = (2 * vi) >> 3;
    const int vcol = (2 * vi) & 7;

    const bool hi2 = (lane >> 5) & 1;   // l4>>1
    const bool bit0 = (lane >> 4) & 1;  // l4&1
    const int sgrp = lane & 48;

    bool mgt[4];
#pragma unroll
    for (int r = 0; r < 4; r++) mgt[r] = (l4 * 4 + r) > l15;

    for (int pass = 0; pass < 2; ++pass) {
        const int qt = pass == 0 ? pairidx : (15 - pairidx);
        const int q0 = qt * 128;
        const int ktmax = 2 * qt + 1;
        const int qwmin = q0 + wl * 16;

        bf16x8 qf[2];
        {
            const u16* qrow = qbase + (size_t)(qwmin + l15) * D3;
            qf[0] = *(const bf16x8*)(qrow + l4 * 8);
            qf[1] = *(const bf16x8*)(qrow + 32 + l4 * 8);
        }

        f32x4 o[4] = {};
        float m_ = -1e30f;   // per q = l15 (uniform across 4-lane group)
        float l_ = 0.f;      // per-lane partial; reduced at epilogue

        u32x2 va, vb_;

        // ---- prologue: stage tile 0 into buf 0 ----
        if (w < 8) {
            GLOAD16(Kg + (size_t)krow * D3 + ksw, &Kt[0][t * 8]);
        } else {
            const u16* vr = Vg + (size_t)(2 * vi) * D3 + vsd;
            va = *(const u32x2*)vr;
            vb_ = *(const u32x2*)(vr + D3);
            asm volatile("s_waitcnt vmcnt(0)" ::: "memory");
            u16 av[4], bv[4];
            *(u32x2*)av = va; *(u32x2*)bv = vb_;
#pragma unroll
            for (int j = 0; j < 4; j++) {
                int d = vsd + j;
                u32 word = (u32)av[j] | ((u32)bv[j] << 16);
                *(u32*)&Vt[0][d * 64 + ((vchunk ^ (d & 7)) << 3) + vcol] = word;
            }
        }
        __syncthreads();

        int cur = 0;
        for (int kt = 0; kt <= ktmax; ++kt) {
            const int k0 = kt * 64;
            const int havenext = (kt < ktmax);

            // ---- issue prefetch of tile kt+1 into buf cur^1 ----
            if (havenext) {
                const int nk0 = k0 + 64;
                if (w < 8) {
                    GLOAD16(Kg + (size_t)(nk0 + krow) * D3 + ksw, &Kt[cur ^ 1][t * 8]);
                } else {
                    const u16* vr = Vg + (size_t)(nk0 + 2 * vi) * D3 + vsd;
                    va = *(const u32x2*)vr;
                    vb_ = *(const u32x2*)(vr + D3);
                }
            }

            const int dks = (qwmin - k0) >> 4;   // <0: skip; 0..3: boundary; >3: full

            if (((kt & 1) == par) && dks >= 0) {
                const int kcm = dks < 3 ? dks : 3;
                const int kgm = (dks >> 1) < 1 ? (dks >> 1) : 1;

                // ---- QK^T over valid slices ----
                f32x4 sv[4];
                float vmax = -3.0e38f;
                __builtin_amdgcn_s_setprio(1);
#pragma unroll
                for (int kc = 0; kc < 4; ++kc) {
                    if (kc <= kcm) {
                        f32x4 s = {};
                        int row = kc * 16 + l15;
                        int sw = row & 7;
                        bf16x8 kf0 = *(const bf16x8*)&Kt[cur][row * 64 + ((l4 ^ sw) << 3)];
                        bf16x8 kf1 = *(const bf16x8*)&Kt[cur][row * 64 + (((4 + l4) ^ sw) << 3)];
                        s = __builtin_amdgcn_mfma_f32_16x16x32_bf16(kf0, qf[0], s, 0, 0, 0);
                        s = __builtin_amdgcn_mfma_f32_16x16x32_bf16(kf1, qf[1], s, 0, 0, 0);
                        const bool bmask = (kc == dks);
#pragma unroll
                        for (int r = 0; r < 4; r++) {
                            float x = s[r];
                            if (bmask && mgt[r]) x = -1e30f;
                            sv[kc][r] = x;
                            vmax = fmaxf(vmax, x);
                        }
                    }
                }
                __builtin_amdgcn_s_setprio(0);

                // ---- one softmax update per 64 cols ----
                vmax = fmaxf(vmax, __shfl_xor(vmax, 16));
                vmax = fmaxf(vmax, __shfl_xor(vmax, 32));

                if (!__all(vmax <= m_ + 8.f)) {     // T13 defer-max
                    float newm = fmaxf(m_, vmax);
                    float corr = fexp2(m_ - newm);
                    l_ *= corr;
                    float corr_o[4];
#pragma unroll
                    for (int r = 0; r < 4; ++r)
                        corr_o[r] = __shfl(corr, sgrp | (((lane >> 4) & 3) * 4 + r));
#pragma unroll
                    for (int db = 0; db < 4; db++)
#pragma unroll
                        for (int r = 0; r < 4; r++) o[db][r] *= corr_o[r];
                    m_ = newm;
                }

                // ---- exp + pack; invalid slices contribute exact zeros ----
                u32 up[4][2];
#pragma unroll
                for (int kc = 0; kc < 4; ++kc) {
                    if (kc <= kcm) {
                        float p0 = fexp2(sv[kc][0] - m_);
                        float p1 = fexp2(sv[kc][1] - m_);
                        float p2 = fexp2(sv[kc][2] - m_);
                        float p3 = fexp2(sv[kc][3] - m_);
                        l_ += (p0 + p1) + (p2 + p3);
                        up[kc][0] = cvtpk_bf16(p0, p1);
                        up[kc][1] = cvtpk_bf16(p2, p3);
                    } else {
                        up[kc][0] = 0u;
                        up[kc][1] = 0u;
                    }
                }

                // ---- transpose network + PV (2 k-groups of 32; skip past-causal) ----
                __builtin_amdgcn_s_setprio(1);
#pragma unroll
                for (int kg = 0; kg < 2; kg++) {
                    if (kg <= kgm) {
                        u32 paya0 = hi2 ? up[2 * kg + 1][0] : up[2 * kg][0];
                        u32 paya1 = hi2 ? up[2 * kg + 1][1] : up[2 * kg][1];
                        u32 payb0 = hi2 ? up[2 * kg][0] : up[2 * kg + 1][0];
                        u32 payb1 = hi2 ? up[2 * kg][1] : up[2 * kg + 1][1];
                        u32 a16_0 = (u32)__shfl_xor((int)paya0, 16);
                        u32 a16_1 = (u32)__shfl_xor((int)paya1, 16);
                        u32 a32_0 = (u32)__shfl_xor((int)payb0, 32);
                        u32 a32_1 = (u32)__shfl_xor((int)payb1, 32);
                        u32 a48_0 = (u32)__shfl_xor((int)payb0, 48);
                        u32 a48_1 = (u32)__shfl_xor((int)payb1, 48);
                        u32x4 tt;
                        tt[0] = hi2 ? (bit0 ? a16_0 : a32_0) : (bit0 ? a48_0 : paya0);
                        tt[1] = hi2 ? (bit0 ? a16_1 : a32_1) : (bit0 ? a48_1 : paya1);
                        tt[2] = hi2 ? (bit0 ? paya0 : a48_0) : (bit0 ? a32_0 : a16_0);
                        tt[3] = hi2 ? (bit0 ? paya1 : a48_1) : (bit0 ? a32_1 : a16_1);
                        union { u32x4 u; bf16x8 b; } pa;
                        pa.u = tt;
#pragma unroll
                        for (int db = 0; db < 4; db++) {
                            int d = db * 16 + l15;
                            bf16x8 vb = *(const bf16x8*)&Vt[cur][d * 64 + (((kg * 4 + l4) ^ (d & 7)) << 3)];
                            o[db] = __builtin_amdgcn_mfma_f32_16x16x32_bf16(pa.b, vb, o[db], 0, 0, 0);
                        }
                    }
                }
                __builtin_amdgcn_s_setprio(0);
            }

            // ---- finish staging tile kt+1 (V write half) ----
            if (havenext && w >= 8) {
                asm volatile("s_waitcnt vmcnt(0)" ::: "memory");
                u16 av[4], bv[4];
                *(u32x2*)av = va; *(u32x2*)bv = vb_;
#pragma unroll
                for (int j = 0; j < 4; j++) {
                    int d = vsd + j;
                    u32 word = (u32)av[j] | ((u32)bv[j] << 16);
                    *(u32*)&Vt[cur ^ 1][d * 64 + ((vchunk ^ (d & 7)) << 3) + vcol] = word;
                }
            }
            __syncthreads();
            cur ^= 1;
        }

        // ---- merge parity-partial states (upper -> LDS -> lower) ----
        if (w >= 8) {
            const int wu = w - 8;
            if (lane < 16) MM[wu * 16 + lane] = m_;
            ML[wu * 64 + lane] = l_;
            float* mo = MO + wu * 1024 + lane * 16;
#pragma unroll
            for (int db = 0; db < 4; db++)
                *(f32x4*)(mo + db * 4) = o[db];
        }
        __syncthreads();
        if (w < 8) {
            float mB = MM[wl * 16 + l15];
            float M = fmaxf(m_, mB);
            float ca = fexp2(m_ - M);
            float cb = fexp2(mB - M);
            l_ = l_ * ca + ML[wl * 64 + lane] * cb;
            float ca_o[4], cb_o[4];
#pragma unroll
            for (int r = 0; r < 4; ++r) {
                int src = sgrp | (((lane >> 4) & 3) * 4 + r);
                ca_o[r] = __shfl(ca, src);
                cb_o[r] = __shfl(cb, src);
            }
            const float* mo = MO + wl * 1024 + lane * 16;
#pragma unroll
            for (int db = 0; db < 4; db++) {
                f32x4 ob = *(const f32x4*)(mo + db * 4);
#pragma unroll
                for (int r = 0; r < 4; r++)
                    o[db][r] = o[db][r] * ca_o[r] + ob[r] * cb_o[r];
            }

            // ---- epilogue: reduce l_ across the q-group, write y ----
            l_ += __shfl_xor(l_, 16);
            l_ += __shfl_xor(l_, 32);
            float linv = 1.f / l_;
            float linv_o[4];
#pragma unroll
            for (int r = 0; r < 4; ++r)
                linv_o[r] = __shfl(linv, sgrp | (((lane >> 4) & 3) * 4 + r));
#pragma unroll
            for (int r = 0; r < 4; r++) {
                int qg = qwmin + l4 * 4 + r;
                u16* yrow = y + (size_t)(b * Nn + qg) * Dd + h * DHd;
#pragma unroll
                for (int db = 0; db < 4; db++)
                    yrow[db * 16 + l15] = f2bf(o[db][r] * linv_o[r]);
            }
        }
        __syncthreads();   // protect pool reuse by next pass staging
    }
}

extern "C" void kernel_launch(void* const* d_in, const int* in_sizes, int n_in,
                              void* d_out, int out_size, void* d_ws, size_t ws_size,
                              hipStream_t stream) {
    const float* x = (const float*)d_in[0];
    const float* Wqkv = (const float*)d_in[1];
    const float* Wout = (const float*)d_in[2];

    char* ws = (char*)d_ws;
    size_t off = 0;
    u16* xb = (u16*)(ws + off);    off += (size_t)Mm * Dd * 2;     // 16 MiB
    u16* wqkvb = (u16*)(ws + off); off += (size_t)D3 * Dd * 2;     //  6 MiB
    u16* woutb = (u16*)(ws + off); off += (size_t)Dd * Dd * 2;     //  2 MiB
    u16* qkv = (u16*)(ws + off);   off += (size_t)Mm * D3 * 2;     // 48 MiB
    u16* yb = (u16*)(ws + off);    off += (size_t)Mm * Dd * 2;     // 16 MiB

    const float SCL = 0.125f * 1.4426950408889634f;  // (1/sqrt(DH)) * log2(e)

    cvt_f32_bf16<<<4096, 256, 0, stream>>>(x, xb, Mm * Dd / 4);
    cvt_f32_bf16_s<<<1024, 256, 0, stream>>>(Wqkv, wqkvb, D3 * Dd / 4, Dd * Dd / 4, SCL);
    cvt_f32_bf16<<<512, 256, 0, stream>>>(Wout, woutb, Dd * Dd / 4);

    gemm_bt<0><<<dim3(D3 / 128, Mm / 128), 256, 0, stream>>>(xb, wqkvb, qkv, Mm, D3, Dd);
    attn<<<dim3(Nn / 256, Bb * Hh), 1024, 0, stream>>>(qkv, yb);
    gemm_bt<1><<<dim3(Dd / 128, Mm / 128), 256, 0, stream>>>(yb, woutb, d_out, Mm, Dd, Dd);
}

// Round 12
// 189.727 us; speedup vs baseline: 1.1081x; 1.1081x over previous
//
#include <hip/hip_runtime.h>
#include <hip/hip_bf16.h>
#include <stdint.h>

#define Bb 4
#define Nn 2048
#define Dd 1024
#define Hh 16
#define DHd 64
#define Mm (Bb*Nn)     /* 8192 */
#define D3 (3*Dd)      /* 3072 */

typedef unsigned short u16;
typedef unsigned int u32;
typedef __attribute__((ext_vector_type(8))) short bf16x8;
typedef __attribute__((ext_vector_type(4))) float f32x4;
typedef __attribute__((ext_vector_type(4))) unsigned int u32x4;

__device__ __forceinline__ u16 f2bf(float f) {
    unsigned int u = __float_as_uint(f);
    u = (u + 0x7FFFu + ((u >> 16) & 1u)) >> 16;
    return (u16)u;
}

__device__ __forceinline__ u32 cvtpk_bf16(float lo, float hi) {
    u32 r;
    asm("v_cvt_pk_bf16_f32 %0, %1, %2" : "=v"(r) : "v"(lo), "v"(hi));
    return r;
}

// bare HW exp2 — no libm guards (inputs bounded by defer-max; -huge underflows to 0)
__device__ __forceinline__ float fexp2(float x) {
    float r;
    asm("v_exp_f32 %0, %1" : "=v"(r) : "v"(x));
    return r;
}

#define GLOAD16(g, l)                                                          \
    __builtin_amdgcn_global_load_lds(                                          \
        (const __attribute__((address_space(1))) unsigned int*)(g),            \
        (__attribute__((address_space(3))) unsigned int*)(l), 16, 0, 0)

// ---------------- fp32 -> bf16 convert ----------------
__global__ void cvt_f32_bf16(const float* __restrict__ in, u16* __restrict__ out, int n4) {
    int i = blockIdx.x * blockDim.x + threadIdx.x;
    int stride = gridDim.x * blockDim.x;
    for (; i < n4; i += stride) {
        float4 v = ((const float4*)in)[i];
        u16 o0 = f2bf(v.x), o1 = f2bf(v.y), o2 = f2bf(v.z), o3 = f2bf(v.w);
        unsigned int lo = (unsigned int)o0 | ((unsigned int)o1 << 16);
        unsigned int hi = (unsigned int)o2 | ((unsigned int)o3 << 16);
        ((uint2*)out)[i] = make_uint2(lo, hi);
    }
}

// convert with scale s applied to flat elements [0, cut4*4) — folds softmax
// scale (and log2e) into the Q-projection rows of W_qkv
__global__ void cvt_f32_bf16_s(const float* __restrict__ in, u16* __restrict__ out,
                               int n4, int cut4, float s) {
    int i = blockIdx.x * blockDim.x + threadIdx.x;
    int stride = gridDim.x * blockDim.x;
    for (; i < n4; i += stride) {
        float4 v = ((const float4*)in)[i];
        float sc = (i < cut4) ? s : 1.0f;
        u16 o0 = f2bf(v.x * sc), o1 = f2bf(v.y * sc), o2 = f2bf(v.z * sc), o3 = f2bf(v.w * sc);
        unsigned int lo = (unsigned int)o0 | ((unsigned int)o1 << 16);
        unsigned int hi = (unsigned int)o2 | ((unsigned int)o3 << 16);
        ((uint2*)out)[i] = make_uint2(lo, hi);
    }
}

// ---------------- bf16 GEMM: C[M][N] = A[M][K] * B[N][K]^T ----------------
// 128x128 tile, BK=64, 256 threads (4 waves 2x2). LDS rows 128B, XOR-swizzled
// at 16B chunks (chunk ^= row&7) via pre-swizzled global source (linear dest).
// T1 XCD swizzle: blocks with linear id ≡ x (mod 8) get a contiguous tile
// chunk -> per-XCD L2 A-panel reuse. Requires grid total % 8 == 0 (holds).
template<int OUT_F32>
__global__ __launch_bounds__(256) void gemm_bt(const u16* __restrict__ A,
                                               const u16* __restrict__ Bm,
                                               void* __restrict__ C,
                                               int M, int Nout, int K) {
    __shared__ u16 As[128 * 64];
    __shared__ u16 Bs[128 * 64];
    const int t = threadIdx.x;
    const int lane = t & 63;
    const int w = t >> 6;
    const int wr = w >> 1, wc = w & 1;
    const int l15 = lane & 15, l4 = lane >> 4;

    const int gx = gridDim.x;
    const int linear = blockIdx.y * gx + blockIdx.x;
    const int cpx = (gx * gridDim.y) >> 3;
    const int tile = (linear & 7) * cpx + (linear >> 3);
    const int m0 = (tile / gx) * 128;
    const int n0 = (tile % gx) * 128;

    f32x4 acc[4][4] = {};

    for (int k0 = 0; k0 < K; k0 += 64) {
        __syncthreads();
#pragma unroll
        for (int i = 0; i < 4; i++) {
            int chunk = i * 256 + t;
            int row = chunk >> 3;
            int csw = ((chunk & 7) ^ (row & 7)) << 3;
            GLOAD16(A + (size_t)(m0 + row) * K + k0 + csw, &As[chunk * 8]);
            GLOAD16(Bm + (size_t)(n0 + row) * K + k0 + csw, &Bs[chunk * 8]);
        }
        __syncthreads();

#pragma unroll
        for (int kh = 0; kh < 2; kh++) {
            bf16x8 a[4], b[4];
#pragma unroll
            for (int mi = 0; mi < 4; mi++) {
                int row = wr * 64 + mi * 16 + l15;
                a[mi] = *(const bf16x8*)&As[row * 64 + (((kh * 4 + l4) ^ (row & 7)) << 3)];
            }
#pragma unroll
            for (int nj = 0; nj < 4; nj++) {
                int row = wc * 64 + nj * 16 + l15;
                b[nj] = *(const bf16x8*)&Bs[row * 64 + (((kh * 4 + l4) ^ (row & 7)) << 3)];
            }
#pragma unroll
            for (int mi = 0; mi < 4; mi++)
#pragma unroll
                for (int nj = 0; nj < 4; nj++)
                    acc[mi][nj] = __builtin_amdgcn_mfma_f32_16x16x32_bf16(a[mi], b[nj], acc[mi][nj], 0, 0, 0);
        }
    }

#pragma unroll
    for (int mi = 0; mi < 4; mi++) {
#pragma unroll
        for (int nj = 0; nj < 4; nj++) {
            int col = n0 + wc * 64 + nj * 16 + l15;
#pragma unroll
            for (int r = 0; r < 4; r++) {
                int row = m0 + wr * 64 + mi * 16 + l4 * 4 + r;
                float v = acc[mi][nj][r];
                if (OUT_F32)
                    ((float*)C)[(size_t)row * Nout + col] = v;
                else
                    ((u16*)C)[(size_t)row * Nout + col] = f2bf(v);
            }
        }
    }
}

// ---------------- causal flash attention ----------------
// grid: (8, 128), 256 threads = 4 waves. XCD remap: bh = bx*8+(by&7) -> all
// blocks of one (b,h) share an XCD L2. pairidx = by>>3; block does 64-row
// q-tiles qt=pairidx and qt=31-pairidx (uniform 33 k-tiles). 4 blocks/CU =
// 4 independent barrier domains (vs r10's 2x8-wave): stalls decorrelate.
// KVBLK=64. Swapped QK^T: lane holds S[k=kc*16+l4*4+r][q=l15] in log2 domain;
// softmax in-register; P -> PV A-fragments via cvt_pk_bf16 + xor-shfl.
// Diagonal: dks=(qwmin-k0)>>4 -> slice bound kcm, PV-group bound kgm,
// boundary mask at kc==dks.
__global__ __launch_bounds__(256, 4) void attn(const u16* __restrict__ qkv, u16* __restrict__ y) {
    __shared__ u16 Kt[2][64 * 64];     // [buf][krow][d]  swizzled 16B chunks: chunk^=(row&7)
    __shared__ u16 Vt[2][64 * 64];     // [buf][d][krow]  swizzled

    const int t = threadIdx.x;         // 0..255
    const int lane = t & 63;
    const int w = t >> 6;              // 0..3
    const int l15 = lane & 15, l4 = lane >> 4;
    const int bh = blockIdx.x * 8 + (blockIdx.y & 7);   // XCD-local K/V
    const int pairidx = blockIdx.y >> 3;                // 0..15
    const int b = bh >> 4, h = bh & 15;

    const u16* qbase = qkv + (size_t)(b * Nn) * D3 + h * DHd;
    const u16* Kg = qbase + Dd;
    const u16* Vg = qbase + 2 * Dd;

    // staging maps: each thread stages 2 K chunks (rows r, r+32) + 1 V row-pair
    const int krow = t >> 3;                  // 0..31
    const int ksw = (((t & 7) ^ (krow & 7)) << 3);   // same for row and row+32
    const int vi = t & 31;                    // V: row pair (2vi, 2vi+1)
    const int vsd = (t >> 5) * 8;             // dims vsd..vsd+7
    const int vchunk = (2 * vi) >> 3;
    const int vcol = (2 * vi) & 7;

    const bool hi2 = (lane >> 5) & 1;   // l4>>1
    const bool bit0 = (lane >> 4) & 1;  // l4&1
    const int sgrp = lane & 48;

    bool mgt[4];
#pragma unroll
    for (int r = 0; r < 4; r++) mgt[r] = (l4 * 4 + r) > l15;

    for (int pass = 0; pass < 2; ++pass) {
        const int qt = pass == 0 ? pairidx : (31 - pairidx);
        const int q0 = qt * 64;
        const int ktmax = qt;
        const int qwmin = q0 + w * 16;

        bf16x8 qf[2];
        {
            const u16* qrow = qbase + (size_t)(qwmin + l15) * D3;
            qf[0] = *(const bf16x8*)(qrow + l4 * 8);
            qf[1] = *(const bf16x8*)(qrow + 32 + l4 * 8);
        }

        f32x4 o[4] = {};
        float m_ = -1e30f;   // per q = l15 (uniform across 4-lane group)
        float l_ = 0.f;      // per-lane partial; reduced at epilogue

        u32x4 va, vb_;

        // ---- prologue: stage tile 0 into buf 0 ----
        GLOAD16(Kg + (size_t)krow * D3 + ksw, &Kt[0][t * 8]);
        GLOAD16(Kg + (size_t)(krow + 32) * D3 + ksw, &Kt[0][(t + 256) * 8]);
        {
            const u16* vr = Vg + (size_t)(2 * vi) * D3 + vsd;
            va = *(const u32x4*)vr;
            vb_ = *(const u32x4*)(vr + D3);
        }
        asm volatile("s_waitcnt vmcnt(0)" ::: "memory");
        {
            u16 av[8], bv[8];
            *(u32x4*)av = va; *(u32x4*)bv = vb_;
#pragma unroll
            for (int j = 0; j < 8; j++) {
                int d = vsd + j;
                u32 word = (u32)av[j] | ((u32)bv[j] << 16);
                *(u32*)&Vt[0][d * 64 + ((vchunk ^ (d & 7)) << 3) + vcol] = word;
            }
        }
        __syncthreads();

        int cur = 0;
        for (int kt = 0; kt <= ktmax; ++kt) {
            const int k0 = kt * 64;
            const int havenext = (kt < ktmax);

            // ---- issue prefetch of tile kt+1 into buf cur^1 ----
            if (havenext) {
                const int nk0 = k0 + 64;
                GLOAD16(Kg + (size_t)(nk0 + krow) * D3 + ksw, &Kt[cur ^ 1][t * 8]);
                GLOAD16(Kg + (size_t)(nk0 + krow + 32) * D3 + ksw, &Kt[cur ^ 1][(t + 256) * 8]);
                const u16* vr = Vg + (size_t)(nk0 + 2 * vi) * D3 + vsd;
                va = *(const u32x4*)vr;
                vb_ = *(const u32x4*)(vr + D3);
            }

            const int dks = (qwmin - k0) >> 4;   // >=0 always; 0..3 on diag tile
            const int kcm = dks < 3 ? dks : 3;
            const int kgm = (dks >> 1) < 1 ? (dks >> 1) : 1;

            // ---- QK^T over valid slices ----
            f32x4 sv[4];
            float vmax = -3.0e38f;
            __builtin_amdgcn_s_setprio(1);
#pragma unroll
            for (int kc = 0; kc < 4; ++kc) {
                if (kc <= kcm) {
                    f32x4 s = {};
                    int row = kc * 16 + l15;
                    int sw = row & 7;
                    bf16x8 kf0 = *(const bf16x8*)&Kt[cur][row * 64 + ((l4 ^ sw) << 3)];
                    bf16x8 kf1 = *(const bf16x8*)&Kt[cur][row * 64 + (((4 + l4) ^ sw) << 3)];
                    s = __builtin_amdgcn_mfma_f32_16x16x32_bf16(kf0, qf[0], s, 0, 0, 0);
                    s = __builtin_amdgcn_mfma_f32_16x16x32_bf16(kf1, qf[1], s, 0, 0, 0);
                    const bool bmask = (kc == dks);
#pragma unroll
                    for (int r = 0; r < 4; r++) {
                        float x = s[r];
                        if (bmask && mgt[r]) x = -1e30f;
                        sv[kc][r] = x;
                        vmax = fmaxf(vmax, x);
                    }
                }
            }
            __builtin_amdgcn_s_setprio(0);

            // ---- one softmax update per 64 cols ----
            vmax = fmaxf(vmax, __shfl_xor(vmax, 16));
            vmax = fmaxf(vmax, __shfl_xor(vmax, 32));

            if (!__all(vmax <= m_ + 8.f)) {     // T13 defer-max
                float newm = fmaxf(m_, vmax);
                float corr = fexp2(m_ - newm);
                l_ *= corr;
                float corr_o[4];
#pragma unroll
                for (int r = 0; r < 4; ++r)
                    corr_o[r] = __shfl(corr, sgrp | (((lane >> 4) & 3) * 4 + r));
#pragma unroll
                for (int db = 0; db < 4; db++)
#pragma unroll
                    for (int r = 0; r < 4; r++) o[db][r] *= corr_o[r];
                m_ = newm;
            }

            // ---- exp + pack; invalid slices contribute exact zeros ----
            u32 up[4][2];
#pragma unroll
            for (int kc = 0; kc < 4; ++kc) {
                if (kc <= kcm) {
                    float p0 = fexp2(sv[kc][0] - m_);
                    float p1 = fexp2(sv[kc][1] - m_);
                    float p2 = fexp2(sv[kc][2] - m_);
                    float p3 = fexp2(sv[kc][3] - m_);
                    l_ += (p0 + p1) + (p2 + p3);
                    up[kc][0] = cvtpk_bf16(p0, p1);
                    up[kc][1] = cvtpk_bf16(p2, p3);
                } else {
                    up[kc][0] = 0u;
                    up[kc][1] = 0u;
                }
            }

            // ---- transpose network + PV (2 k-groups of 32; skip past-causal) ----
            __builtin_amdgcn_s_setprio(1);
#pragma unroll
            for (int kg = 0; kg < 2; kg++) {
                if (kg <= kgm) {
                    u32 paya0 = hi2 ? up[2 * kg + 1][0] : up[2 * kg][0];
                    u32 paya1 = hi2 ? up[2 * kg + 1][1] : up[2 * kg][1];
                    u32 payb0 = hi2 ? up[2 * kg][0] : up[2 * kg + 1][0];
                    u32 payb1 = hi2 ? up[2 * kg][1] : up[2 * kg + 1][1];
                    u32 a16_0 = (u32)__shfl_xor((int)paya0, 16);
                    u32 a16_1 = (u32)__shfl_xor((int)paya1, 16);
                    u32 a32_0 = (u32)__shfl_xor((int)payb0, 32);
                    u32 a32_1 = (u32)__shfl_xor((int)payb1, 32);
                    u32 a48_0 = (u32)__shfl_xor((int)payb0, 48);
                    u32 a48_1 = (u32)__shfl_xor((int)payb1, 48);
                    u32x4 tt;
                    tt[0] = hi2 ? (bit0 ? a16_0 : a32_0) : (bit0 ? a48_0 : paya0);
                    tt[1] = hi2 ? (bit0 ? a16_1 : a32_1) : (bit0 ? a48_1 : paya1);
                    tt[2] = hi2 ? (bit0 ? paya0 : a48_0) : (bit0 ? a32_0 : a16_0);
                    tt[3] = hi2 ? (bit0 ? paya1 : a48_1) : (bit0 ? a32_1 : a16_1);
                    union { u32x4 u; bf16x8 b; } pa;
                    pa.u = tt;
#pragma unroll
                    for (int db = 0; db < 4; db++) {
                        int d = db * 16 + l15;
                        bf16x8 vb = *(const bf16x8*)&Vt[cur][d * 64 + (((kg * 4 + l4) ^ (d & 7)) << 3)];
                        o[db] = __builtin_amdgcn_mfma_f32_16x16x32_bf16(pa.b, vb, o[db], 0, 0, 0);
                    }
                }
            }
            __builtin_amdgcn_s_setprio(0);

            // ---- finish staging tile kt+1 ----
            if (havenext) {
                asm volatile("s_waitcnt vmcnt(0)" ::: "memory");
                u16 av[8], bv[8];
                *(u32x4*)av = va; *(u32x4*)bv = vb_;
#pragma unroll
                for (int j = 0; j < 8; j++) {
                    int d = vsd + j;
                    u32 word = (u32)av[j] | ((u32)bv[j] << 16);
                    *(u32*)&Vt[cur ^ 1][d * 64 + ((vchunk ^ (d & 7)) << 3) + vcol] = word;
                }
            }
            __syncthreads();
            cur ^= 1;
        }

        // ---- epilogue: reduce l_ across the q-group, then write y ----
        l_ += __shfl_xor(l_, 16);
        l_ += __shfl_xor(l_, 32);
        float linv = 1.f / l_;
        float linv_o[4];
#pragma unroll
        for (int r = 0; r < 4; ++r)
            linv_o[r] = __shfl(linv, sgrp | (((lane >> 4) & 3) * 4 + r));
#pragma unroll
        for (int r = 0; r < 4; r++) {
            int qg = qwmin + l4 * 4 + r;
            u16* yrow = y + (size_t)(b * Nn + qg) * Dd + h * DHd;
#pragma unroll
            for (int db = 0; db < 4; db++)
                yrow[db * 16 + l15] = f2bf(o[db][r] * linv_o[r]);
        }
    }
}

extern "C" void kernel_launch(void* const* d_in, const int* in_sizes, int n_in,
                              void* d_out, int out_size, void* d_ws, size_t ws_size,
                              hipStream_t stream) {
    const float* x = (const float*)d_in[0];
    const float* Wqkv = (const float*)d_in[1];
    const float* Wout = (const float*)d_in[2];

    char* ws = (char*)d_ws;
    size_t off = 0;
    u16* xb = (u16*)(ws + off);    off += (size_t)Mm * Dd * 2;     // 16 MiB
    u16* wqkvb = (u16*)(ws + off); off += (size_t)D3 * Dd * 2;     //  6 MiB
    u16* woutb = (u16*)(ws + off); off += (size_t)Dd * Dd * 2;     //  2 MiB
    u16* qkv = (u16*)(ws + off);   off += (size_t)Mm * D3 * 2;     // 48 MiB
    u16* yb = (u16*)(ws + off);    off += (size_t)Mm * Dd * 2;     // 16 MiB

    const float SCL = 0.125f * 1.4426950408889634f;  // (1/sqrt(DH)) * log2(e)

    cvt_f32_bf16<<<4096, 256, 0, stream>>>(x, xb, Mm * Dd / 4);
    cvt_f32_bf16_s<<<1024, 256, 0, stream>>>(Wqkv, wqkvb, D3 * Dd / 4, Dd * Dd / 4, SCL);
    cvt_f32_bf16<<<512, 256, 0, stream>>>(Wout, woutb, Dd * Dd / 4);

    gemm_bt<0><<<dim3(D3 / 128, Mm / 128), 256, 0, stream>>>(xb, wqkvb, qkv, Mm, D3, Dd);
    attn<<<dim3(8, 128), 256, 0, stream>>>(qkv, yb);
    gemm_bt<1><<<dim3(Dd / 128, Mm / 128), 256, 0, stream>>>(yb, woutb, d_out, Mm, Dd, Dd);
}

// Round 13
// 172.903 us; speedup vs baseline: 1.2159x; 1.0973x over previous
//
#include <hip/hip_runtime.h>
#include <hip/hip_bf16.h>
#include <stdint.h>

#define Bb 4
#define Nn 2048
#define Dd 1024
#define Hh 16
#define DHd 64
#define Mm (Bb*Nn)     /* 8192 */
#define D3 (3*Dd)      /* 3072 */

typedef unsigned short u16;
typedef unsigned int u32;
typedef __attribute__((ext_vector_type(8))) short bf16x8;
typedef __attribute__((ext_vector_type(4))) float f32x4;
typedef __attribute__((ext_vector_type(2))) unsigned int u32x2;
typedef __attribute__((ext_vector_type(4))) unsigned int u32x4;

__device__ __forceinline__ u16 f2bf(float f) {
    unsigned int u = __float_as_uint(f);
    u = (u + 0x7FFFu + ((u >> 16) & 1u)) >> 16;
    return (u16)u;
}

__device__ __forceinline__ u32 cvtpk_bf16(float lo, float hi) {
    u32 r;
    asm("v_cvt_pk_bf16_f32 %0, %1, %2" : "=v"(r) : "v"(lo), "v"(hi));
    return r;
}

// bare HW exp2 — no libm guards (inputs bounded by defer-max; -huge underflows to 0)
__device__ __forceinline__ float fexp2(float x) {
    float r;
    asm("v_exp_f32 %0, %1" : "=v"(r) : "v"(x));
    return r;
}

#define GLOAD16(g, l)                                                          \
    __builtin_amdgcn_global_load_lds(                                          \
        (const __attribute__((address_space(1))) unsigned int*)(g),            \
        (__attribute__((address_space(3))) unsigned int*)(l), 16, 0, 0)

// ---------------- fused fp32 -> bf16 convert for all three inputs ----------
// ranges: [0,A4) x -> xb ; [A4,A4+B4) Wqkv -> wqkvb (first QCUT scaled by s,
// folding softmax scale + log2e into Q rows) ; rest Wout -> woutb.
__global__ void cvt_all(const float* __restrict__ x, const float* __restrict__ wqkv,
                        const float* __restrict__ wout, u16* __restrict__ xb,
                        u16* __restrict__ wqkvb, u16* __restrict__ woutb, float s) {
    const int A4 = Mm * Dd / 4;
    const int B4 = D3 * Dd / 4;
    const int C4 = Dd * Dd / 4;
    const int QCUT = Dd * Dd / 4;
    const int total = A4 + B4 + C4;
    int i = blockIdx.x * blockDim.x + threadIdx.x;
    const int stride = gridDim.x * blockDim.x;
    for (; i < total; i += stride) {
        const float* src; u16* dst; int j; float sc = 1.f;
        if (i < A4) { src = x; dst = xb; j = i; }
        else if (i < A4 + B4) { j = i - A4; src = wqkv; dst = wqkvb; if (j < QCUT) sc = s; }
        else { j = i - A4 - B4; src = wout; dst = woutb; }
        float4 v = ((const float4*)src)[j];
        u16 o0 = f2bf(v.x * sc), o1 = f2bf(v.y * sc), o2 = f2bf(v.z * sc), o3 = f2bf(v.w * sc);
        ((uint2*)dst)[j] = make_uint2((u32)o0 | ((u32)o1 << 16), (u32)o2 | ((u32)o3 << 16));
    }
}

// ---------------- bf16 GEMM: C[M][N] = A[M][K] * B[N][K]^T ----------------
// 128x128 tile, BK=64, 256 threads (4 waves 2x2). LDS rows 128B, XOR-swizzled
// at 16B chunks (chunk ^= row&7) via pre-swizzled global source (linear dest).
// T1 XCD swizzle: blocks with linear id ≡ x (mod 8) get a contiguous tile
// chunk -> per-XCD L2 A-panel reuse. Requires grid total % 8 == 0 (holds).
template<int OUT_F32>
__global__ __launch_bounds__(256) void gemm_bt(const u16* __restrict__ A,
                                               const u16* __restrict__ Bm,
                                               void* __restrict__ C,
                                               int M, int Nout, int K) {
    __shared__ u16 As[128 * 64];
    __shared__ u16 Bs[128 * 64];
    const int t = threadIdx.x;
    const int lane = t & 63;
    const int w = t >> 6;
    const int wr = w >> 1, wc = w & 1;
    const int l15 = lane & 15, l4 = lane >> 4;

    const int gx = gridDim.x;
    const int linear = blockIdx.y * gx + blockIdx.x;
    const int cpx = (gx * gridDim.y) >> 3;
    const int tile = (linear & 7) * cpx + (linear >> 3);
    const int m0 = (tile / gx) * 128;
    const int n0 = (tile % gx) * 128;

    f32x4 acc[4][4] = {};

    for (int k0 = 0; k0 < K; k0 += 64) {
        __syncthreads();
#pragma unroll
        for (int i = 0; i < 4; i++) {
            int chunk = i * 256 + t;
            int row = chunk >> 3;
            int csw = ((chunk & 7) ^ (row & 7)) << 3;
            GLOAD16(A + (size_t)(m0 + row) * K + k0 + csw, &As[chunk * 8]);
            GLOAD16(Bm + (size_t)(n0 + row) * K + k0 + csw, &Bs[chunk * 8]);
        }
        __syncthreads();

#pragma unroll
        for (int kh = 0; kh < 2; kh++) {
            bf16x8 a[4], b[4];
#pragma unroll
            for (int mi = 0; mi < 4; mi++) {
                int row = wr * 64 + mi * 16 + l15;
                a[mi] = *(const bf16x8*)&As[row * 64 + (((kh * 4 + l4) ^ (row & 7)) << 3)];
            }
#pragma unroll
            for (int nj = 0; nj < 4; nj++) {
                int row = wc * 64 + nj * 16 + l15;
                b[nj] = *(const bf16x8*)&Bs[row * 64 + (((kh * 4 + l4) ^ (row & 7)) << 3)];
            }
#pragma unroll
            for (int mi = 0; mi < 4; mi++)
#pragma unroll
                for (int nj = 0; nj < 4; nj++)
                    acc[mi][nj] = __builtin_amdgcn_mfma_f32_16x16x32_bf16(a[mi], b[nj], acc[mi][nj], 0, 0, 0);
        }
    }

#pragma unroll
    for (int mi = 0; mi < 4; mi++) {
#pragma unroll
        for (int nj = 0; nj < 4; nj++) {
            int col = n0 + wc * 64 + nj * 16 + l15;
#pragma unroll
            for (int r = 0; r < 4; r++) {
                int row = m0 + wr * 64 + mi * 16 + l4 * 4 + r;
                float v = acc[mi][nj][r];
                if (OUT_F32)
                    ((float*)C)[(size_t)row * Nout + col] = v;
                else
                    ((u16*)C)[(size_t)row * Nout + col] = f2bf(v);
            }
        }
    }
}

// ---------------- causal flash attention (r10 structure) ----------------
// grid: (8, 64). 512 threads = 8 waves. XCD remap: bh = bx*8+(by&7) -> all
// blocks of one (b,h) share an XCD L2 (K/V L2-resident). Each block does
// q-tiles pairidx and 15-pairidx (uniform work). KVBLK=64.
// Swapped QK^T: lane holds S[k=kc*16+l4*4+r][q=l15] in log2 domain; softmax
// in-register; P -> PV A-fragments via cvt_pk_bf16 + xor-shfl butterfly.
// Diagonal per wave: dks=(qwmin-k0)>>4 -> slice bound kcm, PV-group bound kgm,
// boundary mask at kc==dks. Softmax FAST PATH: per-lane max only for the
// defer-max test; cross-lane max shuffles run only when rescaling.
__global__ __launch_bounds__(512) void attn(const u16* __restrict__ qkv, u16* __restrict__ y) {
    __shared__ u16 Kt[2][64 * 64];     // [buf][krow][d]  swizzled 16B chunks: chunk^=(row&7)
    __shared__ u16 Vt[2][64 * 64];     // [buf][d][krow]  swizzled

    const int t = threadIdx.x;
    const int lane = t & 63;
    const int w = t >> 6;
    const int l15 = lane & 15, l4 = lane >> 4;
    const int bh = blockIdx.x * 8 + (blockIdx.y & 7);   // XCD-local K/V
    const int pairidx = blockIdx.y >> 3;
    const int b = bh >> 4, h = bh & 15;

    const u16* qbase = qkv + (size_t)(b * Nn) * D3 + h * DHd;
    const u16* Kg = qbase + Dd;
    const u16* Vg = qbase + 2 * Dd;

    // staging maps
    const int krow = t >> 3;            // K: 512 chunks of 16B, row 0..63
    const int ksw = (((t & 7) ^ (krow & 7)) << 3);
    const int vi = t & 31;              // V: row pair (2vi, 2vi+1)
    const int vsd = (t >> 5) * 4;       // dims vsd..vsd+3
    const int vchunk = (2 * vi) >> 3;
    const int vcol = (2 * vi) & 7;

    const bool hi2 = (lane >> 5) & 1;   // l4>>1
    const bool bit0 = (lane >> 4) & 1;  // l4&1
    const int sgrp = lane & 48;

    bool mgt[4];
#pragma unroll
    for (int r = 0; r < 4; r++) mgt[r] = (l4 * 4 + r) > l15;

    for (int pass = 0; pass < 2; ++pass) {
        const int qt = pass == 0 ? pairidx : (15 - pairidx);
        const int q0 = qt * 128;
        const int ktmax = 2 * qt + 1;
        const int qwmin = q0 + w * 16;

        bf16x8 qf[2];
        {
            const u16* qrow = qbase + (size_t)(qwmin + l15) * D3;
            qf[0] = *(const bf16x8*)(qrow + l4 * 8);
            qf[1] = *(const bf16x8*)(qrow + 32 + l4 * 8);
        }

        f32x4 o[4] = {};
        float m_ = -1e30f;   // per q = l15 (uniform across 4-lane group)
        float l_ = 0.f;      // per-lane partial; reduced at epilogue

        u32x2 va, vb_;

        // ---- prologue: stage tile 0 into buf 0 ----
        GLOAD16(Kg + (size_t)krow * D3 + ksw, &Kt[0][t * 8]);
        {
            const u16* vr = Vg + (size_t)(2 * vi) * D3 + vsd;
            va = *(const u32x2*)vr;
            vb_ = *(const u32x2*)(vr + D3);
        }
        asm volatile("s_waitcnt vmcnt(0)" ::: "memory");
        {
            u16 av[4], bv[4];
            *(u32x2*)av = va; *(u32x2*)bv = vb_;
#pragma unroll
            for (int j = 0; j < 4; j++) {
                int d = vsd + j;
                u32 word = (u32)av[j] | ((u32)bv[j] << 16);
                *(u32*)&Vt[0][d * 64 + ((vchunk ^ (d & 7)) << 3) + vcol] = word;
            }
        }
        __syncthreads();

        int cur = 0;
        for (int kt = 0; kt <= ktmax; ++kt) {
            const int k0 = kt * 64;
            const int havenext = (kt < ktmax);

            // ---- issue prefetch of tile kt+1 into buf cur^1 ----
            if (havenext) {
                const int nk0 = k0 + 64;
                GLOAD16(Kg + (size_t)(nk0 + krow) * D3 + ksw, &Kt[cur ^ 1][t * 8]);
                const u16* vr = Vg + (size_t)(nk0 + 2 * vi) * D3 + vsd;
                va = *(const u32x2*)vr;
                vb_ = *(const u32x2*)(vr + D3);
            }

            const int dks = (qwmin - k0) >> 4;   // <0: skip; 0..3: boundary; >3: full

            if (dks >= 0) {
                const int kcm = dks < 3 ? dks : 3;
                const int kgm = (dks >> 1) < 1 ? (dks >> 1) : 1;

                // ---- QK^T over valid slices ----
                f32x4 sv[4];
                float lm = -3.0e38f;     // per-lane max
                __builtin_amdgcn_s_setprio(1);
#pragma unroll
                for (int kc = 0; kc < 4; ++kc) {
                    if (kc <= kcm) {
                        f32x4 s = {};
                        int row = kc * 16 + l15;
                        int sw = row & 7;
                        bf16x8 kf0 = *(const bf16x8*)&Kt[cur][row * 64 + ((l4 ^ sw) << 3)];
                        bf16x8 kf1 = *(const bf16x8*)&Kt[cur][row * 64 + (((4 + l4) ^ sw) << 3)];
                        s = __builtin_amdgcn_mfma_f32_16x16x32_bf16(kf0, qf[0], s, 0, 0, 0);
                        s = __builtin_amdgcn_mfma_f32_16x16x32_bf16(kf1, qf[1], s, 0, 0, 0);
                        const bool bmask = (kc == dks);
#pragma unroll
                        for (int r = 0; r < 4; r++) {
                            float x = s[r];
                            if (bmask && mgt[r]) x = -1e30f;
                            sv[kc][r] = x;
                            lm = fmaxf(lm, x);
                        }
                    }
                }
                __builtin_amdgcn_s_setprio(0);

                // ---- defer-max fast path: cross-lane reduce only on rescale ----
                if (!__all(lm <= m_ + 8.f)) {
                    float vmax = fmaxf(lm, __shfl_xor(lm, 16));
                    vmax = fmaxf(vmax, __shfl_xor(vmax, 32));
                    float newm = fmaxf(m_, vmax);
                    float corr = fexp2(m_ - newm);
                    l_ *= corr;
                    float corr_o[4];
#pragma unroll
                    for (int r = 0; r < 4; ++r)
                        corr_o[r] = __shfl(corr, sgrp | (((lane >> 4) & 3) * 4 + r));
#pragma unroll
                    for (int db = 0; db < 4; db++)
#pragma unroll
                        for (int r = 0; r < 4; r++) o[db][r] *= corr_o[r];
                    m_ = newm;
                }

                // ---- exp + pack; invalid slices contribute exact zeros ----
                u32 up[4][2];
#pragma unroll
                for (int kc = 0; kc < 4; ++kc) {
                    if (kc <= kcm) {
                        float p0 = fexp2(sv[kc][0] - m_);
                        float p1 = fexp2(sv[kc][1] - m_);
                        float p2 = fexp2(sv[kc][2] - m_);
                        float p3 = fexp2(sv[kc][3] - m_);
                        l_ += (p0 + p1) + (p2 + p3);
                        up[kc][0] = cvtpk_bf16(p0, p1);
                        up[kc][1] = cvtpk_bf16(p2, p3);
                    } else {
                        up[kc][0] = 0u;
                        up[kc][1] = 0u;
                    }
                }

                // ---- transpose network + PV (2 k-groups of 32; skip past-causal) ----
                __builtin_amdgcn_s_setprio(1);
#pragma unroll
                for (int kg = 0; kg < 2; kg++) {
                    if (kg <= kgm) {
                        u32 paya0 = hi2 ? up[2 * kg + 1][0] : up[2 * kg][0];
                        u32 paya1 = hi2 ? up[2 * kg + 1][1] : up[2 * kg][1];
                        u32 payb0 = hi2 ? up[2 * kg][0] : up[2 * kg + 1][0];
                        u32 payb1 = hi2 ? up[2 * kg][1] : up[2 * kg + 1][1];
                        u32 a16_0 = (u32)__shfl_xor((int)paya0, 16);
                        u32 a16_1 = (u32)__shfl_xor((int)paya1, 16);
                        u32 a32_0 = (u32)__shfl_xor((int)payb0, 32);
                        u32 a32_1 = (u32)__shfl_xor((int)payb1, 32);
                        u32 a48_0 = (u32)__shfl_xor((int)payb0, 48);
                        u32 a48_1 = (u32)__shfl_xor((int)payb1, 48);
                        u32x4 tt;
                        tt[0] = hi2 ? (bit0 ? a16_0 : a32_0) : (bit0 ? a48_0 : paya0);
                        tt[1] = hi2 ? (bit0 ? a16_1 : a32_1) : (bit0 ? a48_1 : paya1);
                        tt[2] = hi2 ? (bit0 ? paya0 : a48_0) : (bit0 ? a32_0 : a16_0);
                        tt[3] = hi2 ? (bit0 ? paya1 : a48_1) : (bit0 ? a32_1 : a16_1);
                        union { u32x4 u; bf16x8 b; } pa;
                        pa.u = tt;
#pragma unroll
                        for (int db = 0; db < 4; db++) {
                            int d = db * 16 + l15;
                            bf16x8 vb = *(const bf16x8*)&Vt[cur][d * 64 + (((kg * 4 + l4) ^ (d & 7)) << 3)];
                            o[db] = __builtin_amdgcn_mfma_f32_16x16x32_bf16(pa.b, vb, o[db], 0, 0, 0);
                        }
                    }
                }
                __builtin_amdgcn_s_setprio(0);
            }

            // ---- finish staging tile kt+1 ----
            if (havenext) {
                asm volatile("s_waitcnt vmcnt(0)" ::: "memory");
                u16 av[4], bv[4];
                *(u32x2*)av = va; *(u32x2*)bv = vb_;
#pragma unroll
                for (int j = 0; j < 4; j++) {
                    int d = vsd + j;
                    u32 word = (u32)av[j] | ((u32)bv[j] << 16);
                    *(u32*)&Vt[cur ^ 1][d * 64 + ((vchunk ^ (d & 7)) << 3) + vcol] = word;
                }
            }
            __syncthreads();
            cur ^= 1;
        }

        // ---- epilogue: reduce l_ across the q-group, then write y ----
        l_ += __shfl_xor(l_, 16);
        l_ += __shfl_xor(l_, 32);
        float linv = 1.f / l_;
        float linv_o[4];
#pragma unroll
        for (int r = 0; r < 4; ++r)
            linv_o[r] = __shfl(linv, sgrp | (((lane >> 4) & 3) * 4 + r));
#pragma unroll
        for (int r = 0; r < 4; r++) {
            int qg = qwmin + l4 * 4 + r;
            u16* yrow = y + (size_t)(b * Nn + qg) * Dd + h * DHd;
#pragma unroll
            for (int db = 0; db < 4; db++)
                yrow[db * 16 + l15] = f2bf(o[db][r] * linv_o[r]);
        }
    }
}

extern "C" void kernel_launch(void* const* d_in, const int* in_sizes, int n_in,
                              void* d_out, int out_size, void* d_ws, size_t ws_size,
                              hipStream_t stream) {
    const float* x = (const float*)d_in[0];
    const float* Wqkv = (const float*)d_in[1];
    const float* Wout = (const float*)d_in[2];

    char* ws = (char*)d_ws;
    size_t off = 0;
    u16* xb = (u16*)(ws + off);    off += (size_t)Mm * Dd * 2;     // 16 MiB
    u16* wqkvb = (u16*)(ws + off); off += (size_t)D3 * Dd * 2;     //  6 MiB
    u16* woutb = (u16*)(ws + off); off += (size_t)Dd * Dd * 2;     //  2 MiB
    u16* qkv = (u16*)(ws + off);   off += (size_t)Mm * D3 * 2;     // 48 MiB
    u16* yb = (u16*)(ws + off);    off += (size_t)Mm * Dd * 2;     // 16 MiB

    const float SCL = 0.125f * 1.4426950408889634f;  // (1/sqrt(DH)) * log2(e)

    cvt_all<<<4096, 256, 0, stream>>>(x, Wqkv, Wout, xb, wqkvb, woutb, SCL);

    gemm_bt<0><<<dim3(D3 / 128, Mm / 128), 256, 0, stream>>>(xb, wqkvb, qkv, Mm, D3, Dd);
    attn<<<dim3(8, 64), 512, 0, stream>>>(qkv, yb);
    gemm_bt<1><<<dim3(Dd / 128, Mm / 128), 256, 0, stream>>>(yb, woutb, d_out, Mm, Dd, Dd);
}